// Round 15
// baseline (142.809 us; speedup 1.0000x reference)
//
#include <hip/hip_runtime.h>

// Problem constants: B=8, N=1024, F=128, H=4, K=32, TAU=1
typedef unsigned int uint32;
typedef unsigned short ushort16;

#define P1_PTS 16      // points per A-block
#define P1_BLOCKS 512  // 8192 / P1_PTS
#define NCHUNK_B 64    // chunks per batch = 1024 / P1_PTS

// round-to-nearest-even f32 -> bf16 bits
static __device__ __forceinline__ ushort16 f2bf(float f) {
  uint32 u = __float_as_uint(f);
  return (ushort16)((u + 0x7FFFu + ((u >> 16) & 1u)) >> 16);
}

// ---------------------------------------------------------------------------
// A: per block of 16 points. Thread map: wave w = head w; lane = (khi = l>>2,
// q = l&3); keys {w*32+2khi, w*32+2khi+1}, feature quarter q.
// Dist loop: keys from global (L1-resident rows), x from LDS in a
// quarter-padded layout [p][q][9]f4 (distinct banks per q-group).
// Quarter-combine = shfl_xor 1,2; head-sum = shfl_xor 4,8,16,32 — all
// in-wave, NO accs LDS, no barrier. Then conv-combine + softmax (cross-wave
// via 8KB cwsn), then bf16 partial pooled -> part. LDS 19.2KB -> 4 blk/CU.
// ---------------------------------------------------------------------------
__global__ __launch_bounds__(256, 4) void mempool_A(
    const float* __restrict__ x, const float* __restrict__ keys,
    const float* __restrict__ conv_w, float* __restrict__ S_out,
    uint32* __restrict__ part) {
  const int t = threadIdx.x;
  const int w = t >> 6;    // wave = head
  const int l = t & 63;
  const int q = l & 3;     // feature quarter
  const int khi = l >> 2;  // 0..15

  __shared__ float4 xlp[P1_PTS * 36];    // [p][q][9] (j=8 is pad), 9.2 KB
  __shared__ float cwsn[P1_PTS][4][32];  // [p][h][k], 8 KB
  __shared__ float sl[P1_PTS][32];       // [p][k], 2 KB

  const int bn0 = blockIdx.x * P1_PTS;

  // Stage x into the permuted layout: slot s: p=s>>5, q=(s>>3)&3, j=s&7.
  {
    const float4* xg = reinterpret_cast<const float4*>(x) + (size_t)bn0 * 32;
#pragma unroll
    for (int i = 0; i < 2; ++i) {
      const int s = t + i * 256;
      const int p = s >> 5, r = s & 31;
      xlp[p * 36 + (r >> 3) * 9 + (r & 7)] = xg[s];  // coalesced read
    }
  }
  __syncthreads();

  // Key rows 2khi and 2khi+1 of head w, quarter q (original layout).
  const float4* kr0 = reinterpret_cast<const float4*>(
                          keys + (size_t)(w * 32 + 2 * khi) * 128) +
                      q * 8;
  const float4* kr1 = kr0 + 32;  // next key row (+128 floats)

  float acc0[P1_PTS], acc1[P1_PTS];
#pragma unroll
  for (int p = 0; p < P1_PTS; ++p) acc0[p] = acc1[p] = 0.f;

#pragma unroll
  for (int j = 0; j < 8; ++j) {
    const float4 kv0 = kr0[j];
    const float4 kv1 = kr1[j];
    const float4* xq = &xlp[q * 9 + j];
#pragma unroll
    for (int p = 0; p < P1_PTS; ++p) {
      const float4 xv = xq[p * 36];  // 4 distinct banksets, 16-lane broadcast
      acc0[p] += fabsf(kv0.x - xv.x) + fabsf(kv0.y - xv.y) +
                 fabsf(kv0.z - xv.z) + fabsf(kv0.w - xv.w);
      acc1[p] += fabsf(kv1.x - xv.x) + fabsf(kv1.y - xv.y) +
                 fabsf(kv1.z - xv.z) + fabsf(kv1.w - xv.w);
    }
  }

  // In-wave reduce: quarter-sum (masks 1,2) -> Student-t -> head-sum
  // (masks 4..32) -> normalized cwsn. No LDS, no barrier.
  const float cw = conv_w[w];
#pragma unroll
  for (int p = 0; p < P1_PTS; ++p) {
    float d0 = acc0[p], d1 = acc1[p];
    d0 += __shfl_xor(d0, 1); d0 += __shfl_xor(d0, 2);
    d1 += __shfl_xor(d1, 1); d1 += __shfl_xor(d1, 2);
    const float tv0 = __builtin_amdgcn_rcpf(1.f + d0 * d0);
    const float tv1 = __builtin_amdgcn_rcpf(1.f + d1 * d1);
    float hs = tv0 + tv1;
    hs += __shfl_xor(hs, 4); hs += __shfl_xor(hs, 8);
    hs += __shfl_xor(hs, 16); hs += __shfl_xor(hs, 32);
    const float inv = __builtin_amdgcn_rcpf(hs);
    if (q == 0) cwsn[p][w][2 * khi] = cw * tv0 * inv;
    if (q == 1) cwsn[p][w][2 * khi + 1] = cw * tv1 * inv;
  }
  __syncthreads();

  // Conv-combine over heads + softmax over k. 16 p x 32 k = 2 passes.
#pragma unroll
  for (int pp = 0; pp < 2; ++pp) {
    const int p = pp * 8 + (t >> 5);
    const int k = t & 31;
    float sc = cwsn[p][0][k] + cwsn[p][1][k] + cwsn[p][2][k] + cwsn[p][3][k];
    float mx = sc;
#pragma unroll
    for (int m = 1; m < 32; m <<= 1) mx = fmaxf(mx, __shfl_xor(mx, m));
    const float e = __expf(sc - mx);
    float se = e;
#pragma unroll
    for (int m = 1; m < 32; m <<= 1) se += __shfl_xor(se, m);
    const float sv = e * __builtin_amdgcn_rcpf(se);
    S_out[(size_t)(bn0 + p) * 32 + k] = sv;
    sl[p][k] = sv;
  }
  __syncthreads();

  // Partial pooled (bf16 pairs in uint32), normal cached vector stores.
  // f-index within point p: float4 slot fs*4+i -> xlp[p*36 + q'*9 + j'],
  // q' = fs>>1, j' = (fs&1)*4 + i.
  {
    const int k = t & 31;
    const int fs = t >> 5;
    const float4* xb = &xlp[(fs >> 1) * 9 + (fs & 1) * 4];
    float4 a0 = {0, 0, 0, 0}, a1 = {0, 0, 0, 0}, a2 = {0, 0, 0, 0},
           a3 = {0, 0, 0, 0};
#pragma unroll
    for (int p = 0; p < P1_PTS; ++p) {
      const float s = sl[p][k];
      const float4 v0 = xb[p * 36 + 0];
      const float4 v1 = xb[p * 36 + 1];
      const float4 v2 = xb[p * 36 + 2];
      const float4 v3 = xb[p * 36 + 3];
      a0.x += s * v0.x; a0.y += s * v0.y; a0.z += s * v0.z; a0.w += s * v0.w;
      a1.x += s * v1.x; a1.y += s * v1.y; a1.z += s * v1.z; a1.w += s * v1.w;
      a2.x += s * v2.x; a2.y += s * v2.y; a2.z += s * v2.z; a2.w += s * v2.w;
      a3.x += s * v3.x; a3.y += s * v3.y; a3.z += s * v3.z; a3.w += s * v3.w;
    }
    uint32 w0 = f2bf(a0.x) | ((uint32)f2bf(a0.y) << 16);
    uint32 w1 = f2bf(a0.z) | ((uint32)f2bf(a0.w) << 16);
    uint32 w2 = f2bf(a1.x) | ((uint32)f2bf(a1.y) << 16);
    uint32 w3 = f2bf(a1.z) | ((uint32)f2bf(a1.w) << 16);
    uint32 w4 = f2bf(a2.x) | ((uint32)f2bf(a2.y) << 16);
    uint32 w5 = f2bf(a2.z) | ((uint32)f2bf(a2.w) << 16);
    uint32 w6 = f2bf(a3.x) | ((uint32)f2bf(a3.y) << 16);
    uint32 w7 = f2bf(a3.z) | ((uint32)f2bf(a3.w) << 16);
    uint4* dst = reinterpret_cast<uint4*>(
        part + (((size_t)blockIdx.x * 32 + k) * 64 + fs * 8));
    dst[0] = make_uint4(w0, w1, w2, w3);
    dst[1] = make_uint4(w4, w5, w6, w7);
  }
}

// ---------------------------------------------------------------------------
// Out: block = (b,k), 256 threads (r8/r14-proven).
// ---------------------------------------------------------------------------
__global__ __launch_bounds__(256) void mempool_out(
    const uint32* __restrict__ part, const float* __restrict__ lin_w,
    float* __restrict__ out) {
  const int b = blockIdx.x >> 5;
  const int k = blockIdx.x & 31;
  const int t = threadIdx.x;
  const int f2 = t & 63;
  const int ch = t >> 6;  // 0..3

  __shared__ float red[4][128];
  __shared__ float pooled[128];

  float sx = 0.f, sy = 0.f;
  const uint32* pp =
      part + ((size_t)((b * NCHUNK_B + ch * 16) * 32 + k)) * 64 + f2;
#pragma unroll
  for (int cc = 0; cc < 16; ++cc) {
    const uint32 v = pp[(size_t)cc * 32 * 64];
    sx += __uint_as_float(v << 16);
    sy += __uint_as_float(v & 0xFFFF0000u);
  }
  red[ch][f2 * 2] = sx;
  red[ch][f2 * 2 + 1] = sy;
  __syncthreads();

  if (t < 128) pooled[t] = red[0][t] + red[1][t] + red[2][t] + red[3][t];
  __syncthreads();

  if (t < 128) {
    const float4* w4 = reinterpret_cast<const float4*>(lin_w) + t * 32;
    const float4* pl4 = reinterpret_cast<const float4*>(pooled);
    float o = 0.f;
#pragma unroll
    for (int j = 0; j < 32; ++j) {
      const float4 w = w4[j];
      const float4 p = pl4[j];
      o += w.x * p.x + w.y * p.y + w.z * p.z + w.w * p.w;
    }
    o = (o >= 0.f) ? o : 0.01f * o;
    out[(size_t)(b * 32 + k) * 128 + t] = o;
  }
}

// ---------------------------------------------------------------------------
// Fallbacks (no workspace): round-1 structure (known-good).
// ---------------------------------------------------------------------------
__global__ __launch_bounds__(256) void mempool_phase1_fb(
    const float* __restrict__ x, const float* __restrict__ keys,
    const float* __restrict__ conv_w, float* __restrict__ S_out) {
  const int t = threadIdx.x;
  const int hk = t & 127;
  const int half = t >> 7;

  const float4* kq = reinterpret_cast<const float4*>(keys) + hk * 32 + half * 16;
  const float cw = conv_w[(t >> 5) & 3];

  __shared__ float lds_half[128];
  __shared__ float lds_ws[128];

  const int base = blockIdx.x * 8;
  for (int p = 0; p < 8; ++p) {
    const int bn = base + p;
    const float4* xq = reinterpret_cast<const float4*>(x) + bn * 32 + half * 16;
    float a0 = 0.f;
#pragma unroll
    for (int j = 0; j < 16; ++j) {
      const float4 kv = kq[j];
      const float4 xv = xq[j];
      a0 += fabsf(kv.x - xv.x) + fabsf(kv.y - xv.y) + fabsf(kv.z - xv.z) +
            fabsf(kv.w - xv.w);
    }
    if (t >= 128) lds_half[hk] = a0;
    __syncthreads();
    if (t < 128) {
      const float d = a0 + lds_half[hk];
      const float tv = 1.0f / (1.0f + d * d);
      float hs = tv;
#pragma unroll
      for (int m = 1; m < 32; m <<= 1) hs += __shfl_xor(hs, m);
      lds_ws[hk] = cw * tv / hs;
    }
    __syncthreads();
    if (t < 32) {
      float sc = lds_ws[t] + lds_ws[32 + t] + lds_ws[64 + t] + lds_ws[96 + t];
      float mx = sc;
#pragma unroll
      for (int m = 1; m < 32; m <<= 1) mx = fmaxf(mx, __shfl_xor(mx, m));
      const float e = __expf(sc - mx);
      float se = e;
#pragma unroll
      for (int m = 1; m < 32; m <<= 1) se += __shfl_xor(se, m);
      S_out[bn * 32 + t] = e / se;
    }
    __syncthreads();
  }
}

__global__ __launch_bounds__(256) void mempool_phase2_fb(
    const float* __restrict__ x, const float* __restrict__ S,
    const float* __restrict__ lin_w, float* __restrict__ out) {
  const int b = blockIdx.x >> 5;
  const int k = blockIdx.x & 31;
  const int t = threadIdx.x;
  const int fq = t & 31;
  const int seg = t >> 5;

  const float4* xq = reinterpret_cast<const float4*>(x) + (size_t)b * 1024 * 32;
  const float* Sb = S + (size_t)b * 1024 * 32 + k;

  float4 acc = {0.f, 0.f, 0.f, 0.f};
  const int n0 = seg * 128;
#pragma unroll 4
  for (int n = n0; n < n0 + 128; ++n) {
    const float sv = Sb[(size_t)n * 32];
    const float4 xv = xq[n * 32 + fq];
    acc.x += sv * xv.x;
    acc.y += sv * xv.y;
    acc.z += sv * xv.z;
    acc.w += sv * xv.w;
  }

  __shared__ float4 red[8][32];
  red[seg][fq] = acc;
  __syncthreads();

  __shared__ float4 pooled4[32];
  if (t < 32) {
    float4 a = red[0][t];
#pragma unroll
    for (int ss = 1; ss < 8; ++ss) {
      const float4 r = red[ss][t];
      a.x += r.x; a.y += r.y; a.z += r.z; a.w += r.w;
    }
    pooled4[t] = a;
  }
  __syncthreads();

  if (t < 128) {
    const float4* wq = reinterpret_cast<const float4*>(lin_w) + t * 32;
    float o = 0.f;
#pragma unroll
    for (int j = 0; j < 32; ++j) {
      const float4 w = wq[j];
      const float4 p = pooled4[j];
      o += w.x * p.x + w.y * p.y + w.z * p.z + w.w * p.w;
    }
    o = (o >= 0.f) ? o : 0.01f * o;
    out[(size_t)(b * 32 + k) * 128 + t] = o;
  }
}

extern "C" void kernel_launch(void* const* d_in, const int* in_sizes, int n_in,
                              void* d_out, int out_size, void* d_ws, size_t ws_size,
                              hipStream_t stream) {
  const float* x = (const float*)d_in[0];       // [8,1024,128]
  const float* keys = (const float*)d_in[1];    // [4,32,128]
  const float* conv_w = (const float*)d_in[2];  // [4]
  const float* lin_w = (const float*)d_in[3];   // [128,128]

  float* out = (float*)d_out;            // [8,32,128]
  float* S_out = (float*)d_out + 32768;  // [8,1024,32]

  const size_t part_bytes = (size_t)P1_BLOCKS * 32 * 128 * 2;  // 4 MB bf16

  if (ws_size >= part_bytes) {
    uint32* part = (uint32*)d_ws;
    mempool_A<<<P1_BLOCKS, 256, 0, stream>>>(x, keys, conv_w, S_out, part);
    mempool_out<<<8 * 32, 256, 0, stream>>>(part, lin_w, out);
  } else {
    mempool_phase1_fb<<<1024, 256, 0, stream>>>(x, keys, conv_w, S_out);
    mempool_phase2_fb<<<8 * 32, 256, 0, stream>>>(x, S_out, lin_w, out);
  }
}

// Round 16
// 27.802 us; speedup vs baseline: 5.1366x; 5.1366x over previous
//
#include <hip/hip_runtime.h>

// Problem constants: B=8, N=1024, F=128, H=4, K=32, TAU=1
typedef unsigned int uint32;
typedef unsigned short ushort16;

// round-to-nearest-even f32 -> bf16 bits
static __device__ __forceinline__ ushort16 f2bf(float f) {
  uint32 u = __float_as_uint(f);
  return (ushort16)((u + 0x7FFFu + ((u >> 16) & 1u)) >> 16);
}

// ---------------------------------------------------------------------------
// A<PTS>: per block of PTS points (r14-proven structure, templated).
// Thread = (hkp = t&63, q = t>>6): keys {hkp, hkp+64}, f-quarter q.
// Keys direct from [hk][f] layout (L1-resident rows); x LDS-staged.
// PTS=8 -> 1024 blocks = 4 blocks/CU = 16 waves/CU (2x TLP vs PTS=16),
// acc regs 16 floats, LDS 25 KB. (256,2) keeps the VGPR cap at 128 -> no
// spill (r15's (256,4) squeezed to 64 VGPR and thrashed scratch).
// ---------------------------------------------------------------------------
template <int PTS>
__global__ __launch_bounds__(256, 2) void mempool_A(
    const float* __restrict__ x, const float* __restrict__ keys,
    const float* __restrict__ conv_w, float* __restrict__ S_out,
    uint32* __restrict__ part) {
  const int t = threadIdx.x;
  const int hkp = t & 63;
  const int q = t >> 6;  // f-quarter 0..3

  __shared__ float4 xl[PTS * 32];      // [p][fq]
  __shared__ float accs[PTS][4][128];  // [p][q][hk]
  __shared__ float cwsn[PTS][4][32];   // [p][h][k]
  __shared__ float sl[PTS][32];        // [p][k]

  const int bn0 = blockIdx.x * PTS;

  // Stage x: PTS*32 float4, coalesced.
  {
    const float4* xg = reinterpret_cast<const float4*>(x) + (size_t)bn0 * 32;
#pragma unroll
    for (int i = 0; i < (PTS * 32) / 256; ++i) xl[t + i * 256] = xg[t + i * 256];
  }
  __syncthreads();

  // Key rows hkp and hkp+64, f-quarter q, original layout (L1-resident).
  const float4* kr0 =
      reinterpret_cast<const float4*>(keys + (size_t)hkp * 128 + q * 32);
  const float4* kr1 =
      reinterpret_cast<const float4*>(keys + (size_t)(hkp + 64) * 128 + q * 32);

  float acc0[PTS], acc1[PTS];
#pragma unroll
  for (int p = 0; p < PTS; ++p) acc0[p] = acc1[p] = 0.f;

#pragma unroll
  for (int j = 0; j < 8; ++j) {
    const float4 kv0 = kr0[j];
    const float4 kv1 = kr1[j];
    const int jj = q * 8 + j;
#pragma unroll
    for (int p = 0; p < PTS; ++p) {
      const float4 xv = xl[p * 32 + jj];  // uniform ds_read -> broadcast
      acc0[p] += fabsf(kv0.x - xv.x) + fabsf(kv0.y - xv.y) +
                 fabsf(kv0.z - xv.z) + fabsf(kv0.w - xv.w);
      acc1[p] += fabsf(kv1.x - xv.x) + fabsf(kv1.y - xv.y) +
                 fabsf(kv1.z - xv.z) + fabsf(kv1.w - xv.w);
    }
  }

#pragma unroll
  for (int p = 0; p < PTS; ++p) {
    accs[p][q][hkp] = acc0[p];
    accs[p][q][hkp + 64] = acc1[p];
  }
  __syncthreads();

  // Quarter-combine + Student-t + per-head normalize.
  // PTS*128 cells / 256 threads = PTS/2 each; 32-lane groups share (p,h).
  const float4 cwv = *reinterpret_cast<const float4*>(conv_w);
  {
    const int hk = t & 127;
    const float cw = (hk & 64) ? ((hk & 32) ? cwv.w : cwv.z)
                               : ((hk & 32) ? cwv.y : cwv.x);
#pragma unroll
    for (int i = 0; i < PTS / 2; ++i) {
      const int p = (t >> 7) + 2 * i;
      const float d = accs[p][0][hk] + accs[p][1][hk] + accs[p][2][hk] +
                      accs[p][3][hk];
      const float tv = __builtin_amdgcn_rcpf(1.f + d * d);  // Student-t, tau=1
      float hs = tv;
#pragma unroll
      for (int m = 1; m < 32; m <<= 1) hs += __shfl_xor(hs, m);
      cwsn[p][hk >> 5][hk & 31] = cw * tv * __builtin_amdgcn_rcpf(hs);
    }
  }
  __syncthreads();

  // Conv-combine over heads + softmax over k. PTS p x 32 k, 8 p per pass.
#pragma unroll
  for (int pp = 0; pp < PTS / 8; ++pp) {
    const int p = pp * 8 + (t >> 5);
    const int k = t & 31;
    float sc = cwsn[p][0][k] + cwsn[p][1][k] + cwsn[p][2][k] + cwsn[p][3][k];
    float mx = sc;
#pragma unroll
    for (int m = 1; m < 32; m <<= 1) mx = fmaxf(mx, __shfl_xor(mx, m));
    const float e = __expf(sc - mx);
    float se = e;
#pragma unroll
    for (int m = 1; m < 32; m <<= 1) se += __shfl_xor(se, m);
    const float sv = e * __builtin_amdgcn_rcpf(se);
    S_out[(size_t)(bn0 + p) * 32 + k] = sv;
    sl[p][k] = sv;
  }
  __syncthreads();

  // Partial pooled (bf16 pairs in uint32), normal cached vector stores.
  {
    const int k = t & 31;
    const int fs = t >> 5;
    float4 a0 = {0, 0, 0, 0}, a1 = {0, 0, 0, 0}, a2 = {0, 0, 0, 0},
           a3 = {0, 0, 0, 0};
#pragma unroll
    for (int p = 0; p < PTS; ++p) {
      const float s = sl[p][k];
      const float4 v0 = xl[p * 32 + fs * 4 + 0];
      const float4 v1 = xl[p * 32 + fs * 4 + 1];
      const float4 v2 = xl[p * 32 + fs * 4 + 2];
      const float4 v3 = xl[p * 32 + fs * 4 + 3];
      a0.x += s * v0.x; a0.y += s * v0.y; a0.z += s * v0.z; a0.w += s * v0.w;
      a1.x += s * v1.x; a1.y += s * v1.y; a1.z += s * v1.z; a1.w += s * v1.w;
      a2.x += s * v2.x; a2.y += s * v2.y; a2.z += s * v2.z; a2.w += s * v2.w;
      a3.x += s * v3.x; a3.y += s * v3.y; a3.z += s * v3.z; a3.w += s * v3.w;
    }
    uint32 w0 = f2bf(a0.x) | ((uint32)f2bf(a0.y) << 16);
    uint32 w1 = f2bf(a0.z) | ((uint32)f2bf(a0.w) << 16);
    uint32 w2 = f2bf(a1.x) | ((uint32)f2bf(a1.y) << 16);
    uint32 w3 = f2bf(a1.z) | ((uint32)f2bf(a1.w) << 16);
    uint32 w4 = f2bf(a2.x) | ((uint32)f2bf(a2.y) << 16);
    uint32 w5 = f2bf(a2.z) | ((uint32)f2bf(a2.w) << 16);
    uint32 w6 = f2bf(a3.x) | ((uint32)f2bf(a3.y) << 16);
    uint32 w7 = f2bf(a3.z) | ((uint32)f2bf(a3.w) << 16);
    uint4* dst = reinterpret_cast<uint4*>(
        part + (((size_t)blockIdx.x * 32 + k) * 64 + fs * 8));
    dst[0] = make_uint4(w0, w1, w2, w3);
    dst[1] = make_uint4(w4, w5, w6, w7);
  }
}

// ---------------------------------------------------------------------------
// Out<CHUNKS>: block = (b,k), 256 threads. CHUNKS chunks per batch.
// pooled[f] = sum_c part[b*CHUNKS+c][k][f] (bf16->f32), then matvec+leaky.
// ---------------------------------------------------------------------------
template <int CHUNKS>
__global__ __launch_bounds__(256) void mempool_out(
    const uint32* __restrict__ part, const float* __restrict__ lin_w,
    float* __restrict__ out) {
  const int b = blockIdx.x >> 5;
  const int k = blockIdx.x & 31;
  const int t = threadIdx.x;
  const int f2 = t & 63;
  const int ch = t >> 6;  // 0..3

  __shared__ float red[4][128];
  __shared__ float pooled[128];

  float sx = 0.f, sy = 0.f;
  const uint32* pp =
      part + ((size_t)((b * CHUNKS + ch * (CHUNKS / 4)) * 32 + k)) * 64 + f2;
#pragma unroll
  for (int cc = 0; cc < CHUNKS / 4; ++cc) {
    const uint32 v = pp[(size_t)cc * 32 * 64];
    sx += __uint_as_float(v << 16);
    sy += __uint_as_float(v & 0xFFFF0000u);
  }
  red[ch][f2 * 2] = sx;
  red[ch][f2 * 2 + 1] = sy;
  __syncthreads();

  if (t < 128) pooled[t] = red[0][t] + red[1][t] + red[2][t] + red[3][t];
  __syncthreads();

  if (t < 128) {
    const float4* w4 = reinterpret_cast<const float4*>(lin_w) + t * 32;
    const float4* pl4 = reinterpret_cast<const float4*>(pooled);
    float o = 0.f;
#pragma unroll
    for (int j = 0; j < 32; ++j) {
      const float4 w = w4[j];
      const float4 p = pl4[j];
      o += w.x * p.x + w.y * p.y + w.z * p.z + w.w * p.w;
    }
    o = (o >= 0.f) ? o : 0.01f * o;
    out[(size_t)(b * 32 + k) * 128 + t] = o;
  }
}

// ---------------------------------------------------------------------------
// Fallbacks (no workspace): round-1 structure (known-good).
// ---------------------------------------------------------------------------
__global__ __launch_bounds__(256) void mempool_phase1_fb(
    const float* __restrict__ x, const float* __restrict__ keys,
    const float* __restrict__ conv_w, float* __restrict__ S_out) {
  const int t = threadIdx.x;
  const int hk = t & 127;
  const int half = t >> 7;

  const float4* kq = reinterpret_cast<const float4*>(keys) + hk * 32 + half * 16;
  const float cw = conv_w[(t >> 5) & 3];

  __shared__ float lds_half[128];
  __shared__ float lds_ws[128];

  const int base = blockIdx.x * 8;
  for (int p = 0; p < 8; ++p) {
    const int bn = base + p;
    const float4* xq = reinterpret_cast<const float4*>(x) + bn * 32 + half * 16;
    float a0 = 0.f;
#pragma unroll
    for (int j = 0; j < 16; ++j) {
      const float4 kv = kq[j];
      const float4 xv = xq[j];
      a0 += fabsf(kv.x - xv.x) + fabsf(kv.y - xv.y) + fabsf(kv.z - xv.z) +
            fabsf(kv.w - xv.w);
    }
    if (t >= 128) lds_half[hk] = a0;
    __syncthreads();
    if (t < 128) {
      const float d = a0 + lds_half[hk];
      const float tv = 1.0f / (1.0f + d * d);
      float hs = tv;
#pragma unroll
      for (int m = 1; m < 32; m <<= 1) hs += __shfl_xor(hs, m);
      lds_ws[hk] = cw * tv / hs;
    }
    __syncthreads();
    if (t < 32) {
      float sc = lds_ws[t] + lds_ws[32 + t] + lds_ws[64 + t] + lds_ws[96 + t];
      float mx = sc;
#pragma unroll
      for (int m = 1; m < 32; m <<= 1) mx = fmaxf(mx, __shfl_xor(mx, m));
      const float e = __expf(sc - mx);
      float se = e;
#pragma unroll
      for (int m = 1; m < 32; m <<= 1) se += __shfl_xor(se, m);
      S_out[bn * 32 + t] = e / se;
    }
    __syncthreads();
  }
}

__global__ __launch_bounds__(256) void mempool_phase2_fb(
    const float* __restrict__ x, const float* __restrict__ S,
    const float* __restrict__ lin_w, float* __restrict__ out) {
  const int b = blockIdx.x >> 5;
  const int k = blockIdx.x & 31;
  const int t = threadIdx.x;
  const int fq = t & 31;
  const int seg = t >> 5;

  const float4* xq = reinterpret_cast<const float4*>(x) + (size_t)b * 1024 * 32;
  const float* Sb = S + (size_t)b * 1024 * 32 + k;

  float4 acc = {0.f, 0.f, 0.f, 0.f};
  const int n0 = seg * 128;
#pragma unroll 4
  for (int n = n0; n < n0 + 128; ++n) {
    const float sv = Sb[(size_t)n * 32];
    const float4 xv = xq[n * 32 + fq];
    acc.x += sv * xv.x;
    acc.y += sv * xv.y;
    acc.z += sv * xv.z;
    acc.w += sv * xv.w;
  }

  __shared__ float4 red[8][32];
  red[seg][fq] = acc;
  __syncthreads();

  __shared__ float4 pooled4[32];
  if (t < 32) {
    float4 a = red[0][t];
#pragma unroll
    for (int ss = 1; ss < 8; ++ss) {
      const float4 r = red[ss][t];
      a.x += r.x; a.y += r.y; a.z += r.z; a.w += r.w;
    }
    pooled4[t] = a;
  }
  __syncthreads();

  if (t < 128) {
    const float4* wq = reinterpret_cast<const float4*>(lin_w) + t * 32;
    float o = 0.f;
#pragma unroll
    for (int j = 0; j < 32; ++j) {
      const float4 w = wq[j];
      const float4 p = pooled4[j];
      o += w.x * p.x + w.y * p.y + w.z * p.z + w.w * p.w;
    }
    o = (o >= 0.f) ? o : 0.01f * o;
    out[(size_t)(b * 32 + k) * 128 + t] = o;
  }
}

extern "C" void kernel_launch(void* const* d_in, const int* in_sizes, int n_in,
                              void* d_out, int out_size, void* d_ws, size_t ws_size,
                              hipStream_t stream) {
  const float* x = (const float*)d_in[0];       // [8,1024,128]
  const float* keys = (const float*)d_in[1];    // [4,32,128]
  const float* conv_w = (const float*)d_in[2];  // [4]
  const float* lin_w = (const float*)d_in[3];   // [128,128]

  float* out = (float*)d_out;            // [8,32,128]
  float* S_out = (float*)d_out + 32768;  // [8,1024,32]

  const size_t part8_bytes = (size_t)1024 * 32 * 128 * 2;   // 8 MB (PTS=8)
  const size_t part16_bytes = (size_t)512 * 32 * 128 * 2;   // 4 MB (PTS=16)

  if (ws_size >= part8_bytes) {
    uint32* part = (uint32*)d_ws;
    mempool_A<8><<<1024, 256, 0, stream>>>(x, keys, conv_w, S_out, part);
    mempool_out<128><<<8 * 32, 256, 0, stream>>>(part, lin_w, out);
  } else if (ws_size >= part16_bytes) {
    uint32* part = (uint32*)d_ws;
    mempool_A<16><<<512, 256, 0, stream>>>(x, keys, conv_w, S_out, part);
    mempool_out<64><<<8 * 32, 256, 0, stream>>>(part, lin_w, out);
  } else {
    mempool_phase1_fb<<<1024, 256, 0, stream>>>(x, keys, conv_w, S_out);
    mempool_phase2_fb<<<8 * 32, 256, 0, stream>>>(x, S_out, lin_w, out);
  }
}

// Round 17
// 25.607 us; speedup vs baseline: 5.5769x; 1.0857x over previous
//
#include <hip/hip_runtime.h>

// Problem constants: B=8, N=1024, F=128, H=4, K=32, TAU=1
typedef unsigned int uint32;
typedef unsigned short ushort16;

#define PTS 16         // points per A-block
#define P1_BLOCKS 512  // 8192 / PTS
#define NCHUNK_B 64    // chunks per batch = 1024 / PTS

// round-to-nearest-even f32 -> bf16 bits
static __device__ __forceinline__ ushort16 f2bf(float f) {
  uint32 u = __float_as_uint(f);
  return (ushort16)((u + 0x7FFFu + ((u >> 16) & 1u)) >> 16);
}

// ---------------------------------------------------------------------------
// A: 512 blocks x 512 threads, 16 points/block (r14 structure, 2x waves).
// Thread = (pg = t>>8 point-group of 8, hkp = t&63, q = (t>>6)&3):
// keys {hkp, hkp+64}, f-quarter q, points pg*8..pg*8+8.
// Same traffic and per-block epilogue as r14 (which hit 22.5us at 256thr),
// but 16 waves/CU (4/SIMD) instead of 8 -> 2x latency hiding for the
// ds_read->VALU dist chains (r12 profile: VALUBusy 18%, stall-bound).
// Per-thread acc halves to 16 floats; (512,2) leaves VGPR cap at 256 ->
// no squeeze-spill (r15 lesson). LDS 50KB -> 2 blocks/CU.
// ---------------------------------------------------------------------------
__global__ __launch_bounds__(512, 2) void mempool_A(
    const float* __restrict__ x, const float* __restrict__ keys,
    const float* __restrict__ conv_w, float* __restrict__ S_out,
    uint32* __restrict__ part) {
  const int t = threadIdx.x;
  const int hkp = t & 63;
  const int q = (t >> 6) & 3;  // f-quarter
  const int pg = t >> 8;       // point-group 0/1

  __shared__ float4 xl[PTS * 32];      // [p][fq], 8 KB
  __shared__ float accs[PTS][4][128];  // [p][q][hk], 32 KB
  __shared__ float cwsn[PTS][4][32];   // [p][h][k], 8 KB
  __shared__ float sl[PTS][32];        // [p][k], 2 KB

  const int bn0 = blockIdx.x * PTS;

  // Stage x: 512 float4 = 1 per thread, fully coalesced.
  xl[t] = reinterpret_cast<const float4*>(x)[(size_t)bn0 * 32 + t];
  __syncthreads();

  // Key rows hkp and hkp+64, f-quarter q, original layout (L1-resident).
  const float4* kr0 =
      reinterpret_cast<const float4*>(keys + (size_t)hkp * 128 + q * 32);
  const float4* kr1 =
      reinterpret_cast<const float4*>(keys + (size_t)(hkp + 64) * 128 + q * 32);

  float acc0[8], acc1[8];
#pragma unroll
  for (int p = 0; p < 8; ++p) acc0[p] = acc1[p] = 0.f;

#pragma unroll
  for (int j = 0; j < 8; ++j) {
    const float4 kv0 = kr0[j];
    const float4 kv1 = kr1[j];
    const int jj = q * 8 + j;
#pragma unroll
    for (int p = 0; p < 8; ++p) {
      const float4 xv = xl[(pg * 8 + p) * 32 + jj];  // broadcast ds_read
      acc0[p] += fabsf(kv0.x - xv.x) + fabsf(kv0.y - xv.y) +
                 fabsf(kv0.z - xv.z) + fabsf(kv0.w - xv.w);
      acc1[p] += fabsf(kv1.x - xv.x) + fabsf(kv1.y - xv.y) +
                 fabsf(kv1.z - xv.z) + fabsf(kv1.w - xv.w);
    }
  }

#pragma unroll
  for (int p = 0; p < 8; ++p) {
    accs[pg * 8 + p][q][hkp] = acc0[p];
    accs[pg * 8 + p][q][hkp + 64] = acc1[p];
  }
  __syncthreads();

  // Quarter-combine + Student-t + per-head normalize.
  // 2048 (p,hk) cells / 512 threads = 4 each; 32-lane groups share (p,h).
  const float4 cwv = *reinterpret_cast<const float4*>(conv_w);
  {
    const int hk = t & 127;
    const float cw = (hk & 64) ? ((hk & 32) ? cwv.w : cwv.z)
                               : ((hk & 32) ? cwv.y : cwv.x);
#pragma unroll
    for (int i = 0; i < 4; ++i) {
      const int p = (t >> 7) + 4 * i;
      const float d = accs[p][0][hk] + accs[p][1][hk] + accs[p][2][hk] +
                      accs[p][3][hk];
      const float tv = __builtin_amdgcn_rcpf(1.f + d * d);  // Student-t, tau=1
      float hs = tv;
#pragma unroll
      for (int m = 1; m < 32; m <<= 1) hs += __shfl_xor(hs, m);
      cwsn[p][hk >> 5][hk & 31] = cw * tv * __builtin_amdgcn_rcpf(hs);
    }
  }
  __syncthreads();

  // Conv-combine over heads + softmax over k: 16 p x 32 k = 512 = 1 pass.
  {
    const int p = t >> 5;
    const int k = t & 31;
    float sc = cwsn[p][0][k] + cwsn[p][1][k] + cwsn[p][2][k] + cwsn[p][3][k];
    float mx = sc;
#pragma unroll
    for (int m = 1; m < 32; m <<= 1) mx = fmaxf(mx, __shfl_xor(mx, m));
    const float e = __expf(sc - mx);
    float se = e;
#pragma unroll
    for (int m = 1; m < 32; m <<= 1) se += __shfl_xor(se, m);
    const float sv = e * __builtin_amdgcn_rcpf(se);
    S_out[(size_t)(bn0 + p) * 32 + k] = sv;
    sl[p][k] = sv;
  }
  __syncthreads();

  // Partial pooled (bf16 pairs in uint32): thread = (k = t&31, fs = t>>5
  // in [0,16); features [fs*8, fs*8+8)). One uint4 store per thread.
  {
    const int k = t & 31;
    const int fs = t >> 5;
    float4 a0 = {0, 0, 0, 0}, a1 = {0, 0, 0, 0};
#pragma unroll
    for (int p = 0; p < PTS; ++p) {
      const float s = sl[p][k];
      const float4 v0 = xl[p * 32 + fs * 2 + 0];
      const float4 v1 = xl[p * 32 + fs * 2 + 1];
      a0.x += s * v0.x; a0.y += s * v0.y; a0.z += s * v0.z; a0.w += s * v0.w;
      a1.x += s * v1.x; a1.y += s * v1.y; a1.z += s * v1.z; a1.w += s * v1.w;
    }
    uint32 w0 = f2bf(a0.x) | ((uint32)f2bf(a0.y) << 16);
    uint32 w1 = f2bf(a0.z) | ((uint32)f2bf(a0.w) << 16);
    uint32 w2 = f2bf(a1.x) | ((uint32)f2bf(a1.y) << 16);
    uint32 w3 = f2bf(a1.z) | ((uint32)f2bf(a1.w) << 16);
    reinterpret_cast<uint4*>(
        part + (((size_t)blockIdx.x * 32 + k) * 64))[fs] =
        make_uint4(w0, w1, w2, w3);
  }
}

// ---------------------------------------------------------------------------
// Out: block = (b,k), 256 threads (r8/r14-proven, CHUNKS=64).
// ---------------------------------------------------------------------------
__global__ __launch_bounds__(256) void mempool_out(
    const uint32* __restrict__ part, const float* __restrict__ lin_w,
    float* __restrict__ out) {
  const int b = blockIdx.x >> 5;
  const int k = blockIdx.x & 31;
  const int t = threadIdx.x;
  const int f2 = t & 63;
  const int ch = t >> 6;  // 0..3

  __shared__ float red[4][128];
  __shared__ float pooled[128];

  float sx = 0.f, sy = 0.f;
  const uint32* pp =
      part + ((size_t)((b * NCHUNK_B + ch * 16) * 32 + k)) * 64 + f2;
#pragma unroll
  for (int cc = 0; cc < 16; ++cc) {
    const uint32 v = pp[(size_t)cc * 32 * 64];
    sx += __uint_as_float(v << 16);
    sy += __uint_as_float(v & 0xFFFF0000u);
  }
  red[ch][f2 * 2] = sx;
  red[ch][f2 * 2 + 1] = sy;
  __syncthreads();

  if (t < 128) pooled[t] = red[0][t] + red[1][t] + red[2][t] + red[3][t];
  __syncthreads();

  if (t < 128) {
    const float4* w4 = reinterpret_cast<const float4*>(lin_w) + t * 32;
    const float4* pl4 = reinterpret_cast<const float4*>(pooled);
    float o = 0.f;
#pragma unroll
    for (int j = 0; j < 32; ++j) {
      const float4 w = w4[j];
      const float4 p = pl4[j];
      o += w.x * p.x + w.y * p.y + w.z * p.z + w.w * p.w;
    }
    o = (o >= 0.f) ? o : 0.01f * o;
    out[(size_t)(b * 32 + k) * 128 + t] = o;
  }
}

// ---------------------------------------------------------------------------
// Fallbacks (no workspace): round-1 structure (known-good).
// ---------------------------------------------------------------------------
__global__ __launch_bounds__(256) void mempool_phase1_fb(
    const float* __restrict__ x, const float* __restrict__ keys,
    const float* __restrict__ conv_w, float* __restrict__ S_out) {
  const int t = threadIdx.x;
  const int hk = t & 127;
  const int half = t >> 7;

  const float4* kq = reinterpret_cast<const float4*>(keys) + hk * 32 + half * 16;
  const float cw = conv_w[(t >> 5) & 3];

  __shared__ float lds_half[128];
  __shared__ float lds_ws[128];

  const int base = blockIdx.x * 8;
  for (int p = 0; p < 8; ++p) {
    const int bn = base + p;
    const float4* xq = reinterpret_cast<const float4*>(x) + bn * 32 + half * 16;
    float a0 = 0.f;
#pragma unroll
    for (int j = 0; j < 16; ++j) {
      const float4 kv = kq[j];
      const float4 xv = xq[j];
      a0 += fabsf(kv.x - xv.x) + fabsf(kv.y - xv.y) + fabsf(kv.z - xv.z) +
            fabsf(kv.w - xv.w);
    }
    if (t >= 128) lds_half[hk] = a0;
    __syncthreads();
    if (t < 128) {
      const float d = a0 + lds_half[hk];
      const float tv = 1.0f / (1.0f + d * d);
      float hs = tv;
#pragma unroll
      for (int m = 1; m < 32; m <<= 1) hs += __shfl_xor(hs, m);
      lds_ws[hk] = cw * tv / hs;
    }
    __syncthreads();
    if (t < 32) {
      float sc = lds_ws[t] + lds_ws[32 + t] + lds_ws[64 + t] + lds_ws[96 + t];
      float mx = sc;
#pragma unroll
      for (int m = 1; m < 32; m <<= 1) mx = fmaxf(mx, __shfl_xor(mx, m));
      const float e = __expf(sc - mx);
      float se = e;
#pragma unroll
      for (int m = 1; m < 32; m <<= 1) se += __shfl_xor(se, m);
      S_out[bn * 32 + t] = e / se;
    }
    __syncthreads();
  }
}

__global__ __launch_bounds__(256) void mempool_phase2_fb(
    const float* __restrict__ x, const float* __restrict__ S,
    const float* __restrict__ lin_w, float* __restrict__ out) {
  const int b = blockIdx.x >> 5;
  const int k = blockIdx.x & 31;
  const int t = threadIdx.x;
  const int fq = t & 31;
  const int seg = t >> 5;

  const float4* xq = reinterpret_cast<const float4*>(x) + (size_t)b * 1024 * 32;
  const float* Sb = S + (size_t)b * 1024 * 32 + k;

  float4 acc = {0.f, 0.f, 0.f, 0.f};
  const int n0 = seg * 128;
#pragma unroll 4
  for (int n = n0; n < n0 + 128; ++n) {
    const float sv = Sb[(size_t)n * 32];
    const float4 xv = xq[n * 32 + fq];
    acc.x += sv * xv.x;
    acc.y += sv * xv.y;
    acc.z += sv * xv.z;
    acc.w += sv * xv.w;
  }

  __shared__ float4 red[8][32];
  red[seg][fq] = acc;
  __syncthreads();

  __shared__ float4 pooled4[32];
  if (t < 32) {
    float4 a = red[0][t];
#pragma unroll
    for (int ss = 1; ss < 8; ++ss) {
      const float4 r = red[ss][t];
      a.x += r.x; a.y += r.y; a.z += r.z; a.w += r.w;
    }
    pooled4[t] = a;
  }
  __syncthreads();

  if (t < 128) {
    const float4* wq = reinterpret_cast<const float4*>(lin_w) + t * 32;
    float o = 0.f;
#pragma unroll
    for (int j = 0; j < 32; ++j) {
      const float4 w = wq[j];
      const float4 p = pooled4[j];
      o += w.x * p.x + w.y * p.y + w.z * p.z + w.w * p.w;
    }
    o = (o >= 0.f) ? o : 0.01f * o;
    out[(size_t)(b * 32 + k) * 128 + t] = o;
  }
}

extern "C" void kernel_launch(void* const* d_in, const int* in_sizes, int n_in,
                              void* d_out, int out_size, void* d_ws, size_t ws_size,
                              hipStream_t stream) {
  const float* x = (const float*)d_in[0];       // [8,1024,128]
  const float* keys = (const float*)d_in[1];    // [4,32,128]
  const float* conv_w = (const float*)d_in[2];  // [4]
  const float* lin_w = (const float*)d_in[3];   // [128,128]

  float* out = (float*)d_out;            // [8,32,128]
  float* S_out = (float*)d_out + 32768;  // [8,1024,32]

  const size_t part_bytes = (size_t)P1_BLOCKS * 32 * 128 * 2;  // 4 MB bf16

  if (ws_size >= part_bytes) {
    uint32* part = (uint32*)d_ws;
    mempool_A<<<P1_BLOCKS, 512, 0, stream>>>(x, keys, conv_w, S_out, part);
    mempool_out<<<8 * 32, 256, 0, stream>>>(part, lin_w, out);
  } else {
    mempool_phase1_fb<<<1024, 256, 0, stream>>>(x, keys, conv_w, S_out);
    mempool_phase2_fb<<<8 * 32, 256, 0, stream>>>(x, S_out, lin_w, out);
  }
}

// Round 18
// 22.432 us; speedup vs baseline: 6.3664x; 1.1416x over previous
//
#include <hip/hip_runtime.h>

// Problem constants: B=8, N=1024, F=128, H=4, K=32, TAU=1
typedef unsigned int uint32;
typedef unsigned short ushort16;

#define P1_PTS 16      // points per A-block
#define P1_BLOCKS 512  // 8192 / P1_PTS
#define NCHUNK_B 64    // chunks per batch = 1024 / P1_PTS

// round-to-nearest-even f32 -> bf16 bits
static __device__ __forceinline__ ushort16 f2bf(float f) {
  uint32 u = __float_as_uint(f);
  return (ushort16)((u + 0x7FFFu + ((u >> 16) & 1u)) >> 16);
}

// ---------------------------------------------------------------------------
// A: per block of 16 points: L1 distances (keys read DIRECTLY from the
// original [hk][f] layout — per-thread j-loads walk a 512B row in 16B steps,
// 16KB/wave working set -> L1-cached) -> Student-t -> per-head normalize ->
// conv-combine -> softmax -> S_out, then bf16 partial pooled -> part
// (normal cached stores; kernel boundary provides visibility). This exact
// kernel measured 22.5us total (r14) — best of 17 structural variants:
// grid-limited occupancy (2 blk/CU); more blocks (r16) or fatter blocks
// (r17) both regressed; fusion via device barriers (r9-r13) regressed.
// ---------------------------------------------------------------------------
__global__ __launch_bounds__(256, 2) void mempool_A(
    const float* __restrict__ x, const float* __restrict__ keys,
    const float* __restrict__ conv_w, float* __restrict__ S_out,
    uint32* __restrict__ part) {
  const int t = threadIdx.x;
  const int hkp = t & 63;
  const int q = t >> 6;  // f-quarter 0..3

  __shared__ float4 xl[P1_PTS * 32];      // [p][fq], 8 KB
  __shared__ float accs[P1_PTS][4][128];  // [p][q][hk], 32 KB
  __shared__ float cwsn[P1_PTS][4][32];   // [p][h][k], 8 KB
  __shared__ float sl[P1_PTS][32];        // [p][k], 2 KB

  const int bn0 = blockIdx.x * P1_PTS;

  // Stage x: 512 float4 = 2 per thread, fully coalesced.
  {
    const float4* xg = reinterpret_cast<const float4*>(x) + (size_t)bn0 * 32;
    xl[t] = xg[t];
    xl[t + 256] = xg[t + 256];
  }
  __syncthreads();

  // Key rows hkp and hkp+64, f-quarter q, original layout (L1-resident).
  const float4* kr0 =
      reinterpret_cast<const float4*>(keys + (size_t)hkp * 128 + q * 32);
  const float4* kr1 =
      reinterpret_cast<const float4*>(keys + (size_t)(hkp + 64) * 128 + q * 32);

  float acc0[P1_PTS], acc1[P1_PTS];
#pragma unroll
  for (int p = 0; p < P1_PTS; ++p) acc0[p] = acc1[p] = 0.f;

#pragma unroll
  for (int j = 0; j < 8; ++j) {
    const float4 kv0 = kr0[j];
    const float4 kv1 = kr1[j];
    const int jj = q * 8 + j;
#pragma unroll
    for (int p = 0; p < P1_PTS; ++p) {
      const float4 xv = xl[p * 32 + jj];  // uniform ds_read -> broadcast
      acc0[p] += fabsf(kv0.x - xv.x) + fabsf(kv0.y - xv.y) +
                 fabsf(kv0.z - xv.z) + fabsf(kv0.w - xv.w);
      acc1[p] += fabsf(kv1.x - xv.x) + fabsf(kv1.y - xv.y) +
                 fabsf(kv1.z - xv.z) + fabsf(kv1.w - xv.w);
    }
  }

#pragma unroll
  for (int p = 0; p < P1_PTS; ++p) {
    accs[p][q][hkp] = acc0[p];
    accs[p][q][hkp + 64] = acc1[p];
  }
  __syncthreads();

  // Quarter-combine + Student-t + per-head normalize.
  // 2048 (p,hk) cells / 256 threads = 8 each; 32-lane groups share (p,h).
  const float4 cwv = *reinterpret_cast<const float4*>(conv_w);
  {
    const int hk = t & 127;
    const float cw = (hk & 64) ? ((hk & 32) ? cwv.w : cwv.z)
                               : ((hk & 32) ? cwv.y : cwv.x);
#pragma unroll
    for (int i = 0; i < 8; ++i) {
      const int p = (t >> 7) + 2 * i;
      const float d = accs[p][0][hk] + accs[p][1][hk] + accs[p][2][hk] +
                      accs[p][3][hk];
      const float tv = __builtin_amdgcn_rcpf(1.f + d * d);  // Student-t, tau=1
      float hs = tv;
#pragma unroll
      for (int m = 1; m < 32; m <<= 1) hs += __shfl_xor(hs, m);
      cwsn[p][hk >> 5][hk & 31] = cw * tv * __builtin_amdgcn_rcpf(hs);
    }
  }
  __syncthreads();

  // Conv-combine over heads + softmax over k. 16 p x 32 k = 2 passes.
#pragma unroll
  for (int pp = 0; pp < 2; ++pp) {
    const int p = pp * 8 + (t >> 5);
    const int k = t & 31;
    float sc = cwsn[p][0][k] + cwsn[p][1][k] + cwsn[p][2][k] + cwsn[p][3][k];
    float mx = sc;
#pragma unroll
    for (int m = 1; m < 32; m <<= 1) mx = fmaxf(mx, __shfl_xor(mx, m));
    const float e = __expf(sc - mx);
    float se = e;
#pragma unroll
    for (int m = 1; m < 32; m <<= 1) se += __shfl_xor(se, m);
    const float sv = e * __builtin_amdgcn_rcpf(se);
    S_out[(size_t)(bn0 + p) * 32 + k] = sv;
    sl[p][k] = sv;
  }
  __syncthreads();

  // Partial pooled (bf16 pairs in uint32), normal cached vector stores.
  {
    const int k = t & 31;
    const int fs = t >> 5;
    float4 a0 = {0, 0, 0, 0}, a1 = {0, 0, 0, 0}, a2 = {0, 0, 0, 0},
           a3 = {0, 0, 0, 0};
#pragma unroll
    for (int p = 0; p < P1_PTS; ++p) {
      const float s = sl[p][k];
      const float4 v0 = xl[p * 32 + fs * 4 + 0];
      const float4 v1 = xl[p * 32 + fs * 4 + 1];
      const float4 v2 = xl[p * 32 + fs * 4 + 2];
      const float4 v3 = xl[p * 32 + fs * 4 + 3];
      a0.x += s * v0.x; a0.y += s * v0.y; a0.z += s * v0.z; a0.w += s * v0.w;
      a1.x += s * v1.x; a1.y += s * v1.y; a1.z += s * v1.z; a1.w += s * v1.w;
      a2.x += s * v2.x; a2.y += s * v2.y; a2.z += s * v2.z; a2.w += s * v2.w;
      a3.x += s * v3.x; a3.y += s * v3.y; a3.z += s * v3.z; a3.w += s * v3.w;
    }
    uint32 w0 = f2bf(a0.x) | ((uint32)f2bf(a0.y) << 16);
    uint32 w1 = f2bf(a0.z) | ((uint32)f2bf(a0.w) << 16);
    uint32 w2 = f2bf(a1.x) | ((uint32)f2bf(a1.y) << 16);
    uint32 w3 = f2bf(a1.z) | ((uint32)f2bf(a1.w) << 16);
    uint32 w4 = f2bf(a2.x) | ((uint32)f2bf(a2.y) << 16);
    uint32 w5 = f2bf(a2.z) | ((uint32)f2bf(a2.w) << 16);
    uint32 w6 = f2bf(a3.x) | ((uint32)f2bf(a3.y) << 16);
    uint32 w7 = f2bf(a3.z) | ((uint32)f2bf(a3.w) << 16);
    uint4* dst = reinterpret_cast<uint4*>(
        part + (((size_t)blockIdx.x * 32 + k) * 64 + fs * 8));
    dst[0] = make_uint4(w0, w1, w2, w3);
    dst[1] = make_uint4(w4, w5, w6, w7);
  }
}

// ---------------------------------------------------------------------------
// Out: block = (b,k), 256 threads (r8/r14-proven).
// pooled[f] = sum_{c=0..64} part[b*64+c][k][f] (bf16->f32), then
// out[b][k][fo] = leakyrelu(pooled . lin_w[fo]).
// ---------------------------------------------------------------------------
__global__ __launch_bounds__(256) void mempool_out(
    const uint32* __restrict__ part, const float* __restrict__ lin_w,
    float* __restrict__ out) {
  const int b = blockIdx.x >> 5;
  const int k = blockIdx.x & 31;
  const int t = threadIdx.x;
  const int f2 = t & 63;
  const int ch = t >> 6;  // 0..3

  __shared__ float red[4][128];
  __shared__ float pooled[128];

  float sx = 0.f, sy = 0.f;
  const uint32* pp =
      part + ((size_t)((b * NCHUNK_B + ch * 16) * 32 + k)) * 64 + f2;
#pragma unroll
  for (int cc = 0; cc < 16; ++cc) {
    const uint32 v = pp[(size_t)cc * 32 * 64];
    sx += __uint_as_float(v << 16);
    sy += __uint_as_float(v & 0xFFFF0000u);
  }
  red[ch][f2 * 2] = sx;
  red[ch][f2 * 2 + 1] = sy;
  __syncthreads();

  if (t < 128) pooled[t] = red[0][t] + red[1][t] + red[2][t] + red[3][t];
  __syncthreads();

  if (t < 128) {
    const float4* w4 = reinterpret_cast<const float4*>(lin_w) + t * 32;
    const float4* pl4 = reinterpret_cast<const float4*>(pooled);
    float o = 0.f;
#pragma unroll
    for (int j = 0; j < 32; ++j) {
      const float4 w = w4[j];
      const float4 p = pl4[j];
      o += w.x * p.x + w.y * p.y + w.z * p.z + w.w * p.w;
    }
    o = (o >= 0.f) ? o : 0.01f * o;
    out[(size_t)(b * 32 + k) * 128 + t] = o;
  }
}

// ---------------------------------------------------------------------------
// Fallbacks (no workspace): round-1 structure (known-good).
// ---------------------------------------------------------------------------
__global__ __launch_bounds__(256) void mempool_phase1_fb(
    const float* __restrict__ x, const float* __restrict__ keys,
    const float* __restrict__ conv_w, float* __restrict__ S_out) {
  const int t = threadIdx.x;
  const int hk = t & 127;
  const int half = t >> 7;

  const float4* kq = reinterpret_cast<const float4*>(keys) + hk * 32 + half * 16;
  const float cw = conv_w[(t >> 5) & 3];

  __shared__ float lds_half[128];
  __shared__ float lds_ws[128];

  const int base = blockIdx.x * 8;
  for (int p = 0; p < 8; ++p) {
    const int bn = base + p;
    const float4* xq = reinterpret_cast<const float4*>(x) + bn * 32 + half * 16;
    float a0 = 0.f;
#pragma unroll
    for (int j = 0; j < 16; ++j) {
      const float4 kv = kq[j];
      const float4 xv = xq[j];
      a0 += fabsf(kv.x - xv.x) + fabsf(kv.y - xv.y) + fabsf(kv.z - xv.z) +
            fabsf(kv.w - xv.w);
    }
    if (t >= 128) lds_half[hk] = a0;
    __syncthreads();
    if (t < 128) {
      const float d = a0 + lds_half[hk];
      const float tv = 1.0f / (1.0f + d * d);
      float hs = tv;
#pragma unroll
      for (int m = 1; m < 32; m <<= 1) hs += __shfl_xor(hs, m);
      lds_ws[hk] = cw * tv / hs;
    }
    __syncthreads();
    if (t < 32) {
      float sc = lds_ws[t] + lds_ws[32 + t] + lds_ws[64 + t] + lds_ws[96 + t];
      float mx = sc;
#pragma unroll
      for (int m = 1; m < 32; m <<= 1) mx = fmaxf(mx, __shfl_xor(mx, m));
      const float e = __expf(sc - mx);
      float se = e;
#pragma unroll
      for (int m = 1; m < 32; m <<= 1) se += __shfl_xor(se, m);
      S_out[bn * 32 + t] = e / se;
    }
    __syncthreads();
  }
}

__global__ __launch_bounds__(256) void mempool_phase2_fb(
    const float* __restrict__ x, const float* __restrict__ S,
    const float* __restrict__ lin_w, float* __restrict__ out) {
  const int b = blockIdx.x >> 5;
  const int k = blockIdx.x & 31;
  const int t = threadIdx.x;
  const int fq = t & 31;
  const int seg = t >> 5;

  const float4* xq = reinterpret_cast<const float4*>(x) + (size_t)b * 1024 * 32;
  const float* Sb = S + (size_t)b * 1024 * 32 + k;

  float4 acc = {0.f, 0.f, 0.f, 0.f};
  const int n0 = seg * 128;
#pragma unroll 4
  for (int n = n0; n < n0 + 128; ++n) {
    const float sv = Sb[(size_t)n * 32];
    const float4 xv = xq[n * 32 + fq];
    acc.x += sv * xv.x;
    acc.y += sv * xv.y;
    acc.z += sv * xv.z;
    acc.w += sv * xv.w;
  }

  __shared__ float4 red[8][32];
  red[seg][fq] = acc;
  __syncthreads();

  __shared__ float4 pooled4[32];
  if (t < 32) {
    float4 a = red[0][t];
#pragma unroll
    for (int ss = 1; ss < 8; ++ss) {
      const float4 r = red[ss][t];
      a.x += r.x; a.y += r.y; a.z += r.z; a.w += r.w;
    }
    pooled4[t] = a;
  }
  __syncthreads();

  if (t < 128) {
    const float4* wq = reinterpret_cast<const float4*>(lin_w) + t * 32;
    float o = 0.f;
#pragma unroll
    for (int j = 0; j < 32; ++j) {
      const float4 w = wq[j];
      const float4 p = pooled4[j];
      o += w.x * p.x + w.y * p.y + w.z * p.z + w.w * p.w;
    }
    o = (o >= 0.f) ? o : 0.01f * o;
    out[(size_t)(b * 32 + k) * 128 + t] = o;
  }
}

extern "C" void kernel_launch(void* const* d_in, const int* in_sizes, int n_in,
                              void* d_out, int out_size, void* d_ws, size_t ws_size,
                              hipStream_t stream) {
  const float* x = (const float*)d_in[0];       // [8,1024,128]
  const float* keys = (const float*)d_in[1];    // [4,32,128]
  const float* conv_w = (const float*)d_in[2];  // [4]
  const float* lin_w = (const float*)d_in[3];   // [128,128]

  float* out = (float*)d_out;            // [8,32,128]
  float* S_out = (float*)d_out + 32768;  // [8,1024,32]

  const size_t part_bytes = (size_t)P1_BLOCKS * 32 * 128 * 2;  // 4 MB bf16

  if (ws_size >= part_bytes) {
    uint32* part = (uint32*)d_ws;
    mempool_A<<<P1_BLOCKS, 256, 0, stream>>>(x, keys, conv_w, S_out, part);
    mempool_out<<<8 * 32, 256, 0, stream>>>(part, lin_w, out);
  } else {
    mempool_phase1_fb<<<1024, 256, 0, stream>>>(x, keys, conv_w, S_out);
    mempool_phase2_fb<<<8 * 32, 256, 0, stream>>>(x, S_out, lin_w, out);
  }
}